// Round 1
// baseline (2314.689 us; speedup 1.0000x reference)
//
#include <hip/hip_runtime.h>
#include <math.h>

// Problem constants
static constexpr int Bc = 128;   // batch
static constexpr int Mc = 256;   // text tokens
static constexpr int Nc = 1024;  // patches
static constexpr int Dc = 256;   // dim

__device__ __forceinline__ float gelu_exact(float x) {
    return 0.5f * x * (1.0f + erff(x * 0.70710678118654752440f));
}

// ---------------------------------------------------------------------------
// 1) L2-normalize rows of vis [B,N,D] and txt [B,M,D]  (wave per row, D=256)
__global__ void normalize_kernel(const float* __restrict__ vis,
                                 const float* __restrict__ txt,
                                 float* __restrict__ vis_n,
                                 float* __restrict__ txt_n) {
    int wave = (blockIdx.x * blockDim.x + threadIdx.x) >> 6;
    int lane = threadIdx.x & 63;
    const int visRows = Bc * Nc;
    const int total = visRows + Bc * Mc;
    if (wave >= total) return;
    const float* src; float* dst; long long row;
    if (wave < visRows) { src = vis; dst = vis_n; row = wave; }
    else { src = txt; dst = txt_n; row = wave - visRows; }
    const float4* s4 = (const float4*)(src + row * Dc);
    float4* d4 = (float4*)(dst + row * Dc);
    float4 v = s4[lane];                      // 64 lanes * 4 = 256
    float ss = v.x * v.x + v.y * v.y + v.z * v.z + v.w * v.w;
    #pragma unroll
    for (int off = 32; off; off >>= 1) ss += __shfl_xor(ss, off);
    float scale = 1.0f / fmaxf(sqrtf(ss), 1e-8f);
    v.x *= scale; v.y *= scale; v.z *= scale; v.w *= scale;
    d4[lane] = v;
}

// ---------------------------------------------------------------------------
// 2) sim[b] = txt_n[b] (MxD) * vis_n[b]^T (NxD)  — GEMM-NT, 64x64 tile, 4x4/thread
__global__ __launch_bounds__(256) void simgemm_kernel(const float* __restrict__ txt_n,
                                                      const float* __restrict__ vis_n,
                                                      float* __restrict__ sim) {
    __shared__ float As[64][68];
    __shared__ float Bs[64][68];
    int b = blockIdx.z;
    int m0 = blockIdx.y * 64;
    int n0 = blockIdx.x * 64;
    const float* A = txt_n + (long long)b * Mc * Dc;
    const float* Bp = vis_n + (long long)b * Nc * Dc;
    int tid = threadIdx.x;
    int tx = tid & 15, ty = tid >> 4;
    float acc[4][4] = {};
    for (int k0 = 0; k0 < Dc; k0 += 64) {
        #pragma unroll
        for (int i = 0; i < 4; i++) {
            int j = tid + i * 256;
            int r = j >> 4;
            int c4 = (j & 15) << 2;
            *(float4*)(&As[r][c4]) = *(const float4*)(A + (long long)(m0 + r) * Dc + k0 + c4);
            *(float4*)(&Bs[r][c4]) = *(const float4*)(Bp + (long long)(n0 + r) * Dc + k0 + c4);
        }
        __syncthreads();
        #pragma unroll
        for (int k4 = 0; k4 < 16; k4++) {
            float4 a4[4], b4[4];
            #pragma unroll
            for (int r = 0; r < 4; r++) a4[r] = *(const float4*)(&As[ty * 4 + r][k4 * 4]);
            #pragma unroll
            for (int c = 0; c < 4; c++) b4[c] = *(const float4*)(&Bs[tx * 4 + c][k4 * 4]);
            #pragma unroll
            for (int r = 0; r < 4; r++)
                #pragma unroll
                for (int c = 0; c < 4; c++)
                    acc[r][c] += a4[r].x * b4[c].x + a4[r].y * b4[c].y +
                                 a4[r].z * b4[c].z + a4[r].w * b4[c].w;
        }
        __syncthreads();
    }
    float* C = sim + (long long)b * Mc * Nc;
    #pragma unroll
    for (int r = 0; r < 4; r++) {
        float4 o = make_float4(acc[r][0], acc[r][1], acc[r][2], acc[r][3]);
        *(float4*)(C + (long long)(m0 + ty * 4 + r) * Nc + n0 + tx * 4) = o;
    }
}

// ---------------------------------------------------------------------------
// 3) per-(b,m): max/argmax over n (pre-mask), write tms (masked), idx (float),
//    logits; then overwrite masked sim rows with -1.  Wave per row.
__global__ void rowstats_kernel(float* __restrict__ sim,
                                const int* __restrict__ mask,
                                float* __restrict__ tms_out,
                                float* __restrict__ idx_out,
                                float* __restrict__ logits_out,
                                int* __restrict__ idx_ws) {
    int wave = (blockIdx.x * blockDim.x + threadIdx.x) >> 6;
    int lane = threadIdx.x & 63;
    if (wave >= Bc * Mc) return;
    float* row = sim + (long long)wave * Nc;
    float best = -3.0e38f; int bi = 0;
    #pragma unroll
    for (int s = 0; s < Nc; s += 256) {
        int base = s + lane * 4;
        float4 v = *(const float4*)(row + base);
        if (v.x > best) { best = v.x; bi = base; }
        if (v.y > best) { best = v.y; bi = base + 1; }
        if (v.z > best) { best = v.z; bi = base + 2; }
        if (v.w > best) { best = v.w; bi = base + 3; }
    }
    #pragma unroll
    for (int off = 32; off; off >>= 1) {
        float ov = __shfl_xor(best, off);
        int oi = __shfl_xor(bi, off);
        if (ov > best || (ov == best && oi < bi)) { best = ov; bi = oi; }
    }
    int mk = mask[wave];
    if (lane == 0) {
        float tms = mk ? best : 0.0f;
        tms_out[wave] = tms;
        idx_out[wave] = (float)bi;
        idx_ws[wave] = bi;
        float pf = fminf(fmaxf(tms, 0.0f), 1.0f);
        logits_out[wave * 2 + 0] = 1.0f - pf;
        logits_out[wave * 2 + 1] = pf;
    }
    if (mk == 0) {
        float4 mv = make_float4(-1.0f, -1.0f, -1.0f, -1.0f);
        #pragma unroll
        for (int s = 0; s < Nc; s += 256) *(float4*)(row + s + lane * 4) = mv;
    }
}

// ---------------------------------------------------------------------------
// 4) column softmax stats over m for sim^T: cmax[b,n], crecip[b,n]=1/sum(exp)
__global__ void colstats_kernel(const float* __restrict__ sim,
                                float* __restrict__ cmax,
                                float* __restrict__ crecip) {
    int b = blockIdx.y;
    int n = blockIdx.x * 256 + threadIdx.x;
    const float* base = sim + (long long)b * Mc * Nc + n;
    float mx = -3.0e38f;
    for (int m = 0; m < Mc; m++) mx = fmaxf(mx, base[(long long)m * Nc]);
    float s = 0.0f;
    for (int m = 0; m < Mc; m++) s += expf(base[(long long)m * Nc] - mx);
    cmax[b * Nc + n] = mx;
    crecip[b * Nc + n] = 1.0f / s;
}

// ---------------------------------------------------------------------------
// 5) weighted_patch[b] = softmax_m(sim^T) (NxM) * txt_n[b] (MxD)
__global__ __launch_bounds__(256) void wpgemm_kernel(const float* __restrict__ sim,
                                                     const float* __restrict__ txt_n,
                                                     const float* __restrict__ cmax,
                                                     const float* __restrict__ crecip,
                                                     float* __restrict__ wp) {
    __shared__ float Ps[64][68];  // [n][m]
    __shared__ float Ts[64][68];  // [m][d]
    __shared__ float cmx[64], crc[64];
    int b = blockIdx.z;
    int n0 = blockIdx.y * 64;
    int d0 = blockIdx.x * 64;
    int tid = threadIdx.x, tx = tid & 15, ty = tid >> 4;
    if (tid < 64) { cmx[tid] = cmax[b * Nc + n0 + tid]; crc[tid] = crecip[b * Nc + n0 + tid]; }
    __syncthreads();
    float acc[4][4] = {};
    const float* S = sim + (long long)b * Mc * Nc;
    const float* T = txt_n + (long long)b * Mc * Dc;
    for (int m0 = 0; m0 < Mc; m0 += 64) {
        #pragma unroll
        for (int i = 0; i < 4; i++) {
            int j = tid + i * 256;
            int r = j >> 4;          // m within tile
            int c4 = (j & 15) << 2;  // n (for Ps) / d (for Ts)
            float4 v = *(const float4*)(S + (long long)(m0 + r) * Nc + n0 + c4);
            Ps[c4 + 0][r] = expf(v.x - cmx[c4 + 0]) * crc[c4 + 0];
            Ps[c4 + 1][r] = expf(v.y - cmx[c4 + 1]) * crc[c4 + 1];
            Ps[c4 + 2][r] = expf(v.z - cmx[c4 + 2]) * crc[c4 + 2];
            Ps[c4 + 3][r] = expf(v.w - cmx[c4 + 3]) * crc[c4 + 3];
            *(float4*)(&Ts[r][c4]) = *(const float4*)(T + (long long)(m0 + r) * Dc + d0 + c4);
        }
        __syncthreads();
        #pragma unroll
        for (int k4 = 0; k4 < 16; k4++) {
            float4 a4[4], bk[4];
            #pragma unroll
            for (int r = 0; r < 4; r++) a4[r] = *(const float4*)(&Ps[ty * 4 + r][k4 * 4]);
            #pragma unroll
            for (int kk = 0; kk < 4; kk++) bk[kk] = *(const float4*)(&Ts[k4 * 4 + kk][tx * 4]);
            #pragma unroll
            for (int r = 0; r < 4; r++) {
                acc[r][0] += a4[r].x * bk[0].x + a4[r].y * bk[1].x + a4[r].z * bk[2].x + a4[r].w * bk[3].x;
                acc[r][1] += a4[r].x * bk[0].y + a4[r].y * bk[1].y + a4[r].z * bk[2].y + a4[r].w * bk[3].y;
                acc[r][2] += a4[r].x * bk[0].z + a4[r].y * bk[1].z + a4[r].z * bk[2].z + a4[r].w * bk[3].z;
                acc[r][3] += a4[r].x * bk[0].w + a4[r].y * bk[1].w + a4[r].z * bk[2].w + a4[r].w * bk[3].w;
            }
        }
        __syncthreads();
    }
    float* W = wp + (long long)b * Nc * Dc;
    #pragma unroll
    for (int r = 0; r < 4; r++) {
        float4 o = make_float4(acc[r][0], acc[r][1], acc[r][2], acc[r][3]);
        *(float4*)(W + (long long)(n0 + ty * 4 + r) * Dc + d0 + tx * 4) = o;
    }
}

// ---------------------------------------------------------------------------
// 6) pair[b,m] = [txt_n[b,m], vis_n[b, idx]]  (wave per row)
__global__ void gatherpair_kernel(const float* __restrict__ txt_n,
                                  const float* __restrict__ vis_n,
                                  const int* __restrict__ idx_ws,
                                  float* __restrict__ pairbuf) {
    int wave = (blockIdx.x * blockDim.x + threadIdx.x) >> 6;
    int lane = threadIdx.x & 63;
    if (wave >= Bc * Mc) return;
    int b = wave / Mc;
    int bi = idx_ws[wave];
    const float4* t4 = (const float4*)(txt_n + (long long)wave * Dc);
    const float4* v4 = (const float4*)(vis_n + ((long long)b * Nc + bi) * Dc);
    float4* p4 = (float4*)(pairbuf + (long long)wave * 2 * Dc);
    p4[lane] = t4[lane];
    p4[64 + lane] = v4[lane];
}

// ---------------------------------------------------------------------------
// 7) generic GEMM-NN: C[MRxNCOL] = act(A[MRxK] * Bw[KxNCOL] + bias), NCOL=256
template <int ACT>
__global__ __launch_bounds__(256) void gemmnn_kernel(const float* __restrict__ A,
                                                     const float* __restrict__ Bw,
                                                     const float* __restrict__ bias,
                                                     float* __restrict__ C,
                                                     int MR, int K, int NCOL) {
    __shared__ float As[64][68];
    __shared__ float Bs[64][68];
    int m0 = blockIdx.y * 64;
    int n0 = blockIdx.x * 64;
    int tid = threadIdx.x, tx = tid & 15, ty = tid >> 4;
    float acc[4][4] = {};
    for (int k0 = 0; k0 < K; k0 += 64) {
        #pragma unroll
        for (int i = 0; i < 4; i++) {
            int j = tid + i * 256;
            int r = j >> 4;
            int c4 = (j & 15) << 2;
            *(float4*)(&As[r][c4]) = *(const float4*)(A + (long long)(m0 + r) * K + k0 + c4);
            *(float4*)(&Bs[r][c4]) = *(const float4*)(Bw + (long long)(k0 + r) * NCOL + n0 + c4);
        }
        __syncthreads();
        #pragma unroll
        for (int k4 = 0; k4 < 16; k4++) {
            float4 a4[4], bk[4];
            #pragma unroll
            for (int r = 0; r < 4; r++) a4[r] = *(const float4*)(&As[ty * 4 + r][k4 * 4]);
            #pragma unroll
            for (int kk = 0; kk < 4; kk++) bk[kk] = *(const float4*)(&Bs[k4 * 4 + kk][tx * 4]);
            #pragma unroll
            for (int r = 0; r < 4; r++) {
                acc[r][0] += a4[r].x * bk[0].x + a4[r].y * bk[1].x + a4[r].z * bk[2].x + a4[r].w * bk[3].x;
                acc[r][1] += a4[r].x * bk[0].y + a4[r].y * bk[1].y + a4[r].z * bk[2].y + a4[r].w * bk[3].y;
                acc[r][2] += a4[r].x * bk[0].z + a4[r].y * bk[1].z + a4[r].z * bk[2].z + a4[r].w * bk[3].z;
                acc[r][3] += a4[r].x * bk[0].w + a4[r].y * bk[1].w + a4[r].z * bk[2].w + a4[r].w * bk[3].w;
            }
        }
        __syncthreads();
    }
    float4 bb = *(const float4*)(bias + n0 + tx * 4);
    #pragma unroll
    for (int r = 0; r < 4; r++) {
        float4 o;
        o.x = acc[r][0] + bb.x; o.y = acc[r][1] + bb.y;
        o.z = acc[r][2] + bb.z; o.w = acc[r][3] + bb.w;
        if (ACT == 1) { o.x = gelu_exact(o.x); o.y = gelu_exact(o.y); o.z = gelu_exact(o.z); o.w = gelu_exact(o.w); }
        *(float4*)(C + (long long)(m0 + ty * 4 + r) * NCOL + n0 + tx * 4) = o;
    }
}

// ---------------------------------------------------------------------------
// 8) LayerNorm + GELU in place over rows of H [B*M, D]
__global__ void lngelu_kernel(float* __restrict__ H,
                              const float* __restrict__ g,
                              const float* __restrict__ bta) {
    int wave = (blockIdx.x * blockDim.x + threadIdx.x) >> 6;
    int lane = threadIdx.x & 63;
    if (wave >= Bc * Mc) return;
    float4* h4 = (float4*)(H + (long long)wave * Dc);
    float4 v = h4[lane];
    float s = v.x + v.y + v.z + v.w;
    #pragma unroll
    for (int off = 32; off; off >>= 1) s += __shfl_xor(s, off);
    float mu = s * (1.0f / 256.0f);
    float dx = v.x - mu, dy = v.y - mu, dz = v.z - mu, dw = v.w - mu;
    float ss = dx * dx + dy * dy + dz * dz + dw * dw;
    #pragma unroll
    for (int off = 32; off; off >>= 1) ss += __shfl_xor(ss, off);
    float rstd = 1.0f / sqrtf(ss * (1.0f / 256.0f) + 1e-5f);
    float4 G4 = ((const float4*)g)[lane];
    float4 B4 = ((const float4*)bta)[lane];
    v.x = gelu_exact(dx * rstd * G4.x + B4.x);
    v.y = gelu_exact(dy * rstd * G4.y + B4.y);
    v.z = gelu_exact(dz * rstd * G4.z + B4.z);
    v.w = gelu_exact(dw * rstd * G4.w + B4.w);
    h4[lane] = v;
}

// ---------------------------------------------------------------------------
// 9) gate_raw[b,m] = G[b,m,:] . Wg2 + bg2   (wave per row)
__global__ void gate_kernel(const float* __restrict__ G,
                            const float* __restrict__ Wg2,
                            const float* __restrict__ bg2,
                            float* __restrict__ gate) {
    int wave = (blockIdx.x * blockDim.x + threadIdx.x) >> 6;
    int lane = threadIdx.x & 63;
    if (wave >= Bc * Mc) return;
    float4 v = ((const float4*)(G + (long long)wave * Dc))[lane];
    float4 w = ((const float4*)Wg2)[lane];
    float s = v.x * w.x + v.y * w.y + v.z * w.z + v.w * w.w;
    #pragma unroll
    for (int off = 32; off; off >>= 1) s += __shfl_xor(s, off);
    if (lane == 0) gate[wave] = s + bg2[0];
}

// ---------------------------------------------------------------------------
// 10) per-b: gate softmax (mask -> -1e4, softmax, *mask, renorm), grounding,
//     contradiction, feat, score MLP.  One block (256 threads) per b.
__global__ __launch_bounds__(256) void final_kernel(const float* __restrict__ gate,
                                                    const int* __restrict__ mask,
                                                    const float* __restrict__ tms,
                                                    const float* __restrict__ pairO,
                                                    const float* __restrict__ Ws1,
                                                    const float* __restrict__ bs1,
                                                    const float* __restrict__ Ws2,
                                                    const float* __restrict__ bs2,
                                                    float* __restrict__ grounding_out,
                                                    float* __restrict__ score_out) {
    __shared__ float wS[256];
    __shared__ float featS[256];
    __shared__ float hS[128];
    __shared__ float red4[4];
    int b = blockIdx.x, t = threadIdx.x;
    int mk = mask[b * Mc + t];
    float g = mk ? gate[b * Mc + t] : -10000.0f;

    float mx = g;
    #pragma unroll
    for (int off = 32; off; off >>= 1) mx = fmaxf(mx, __shfl_xor(mx, off));
    if ((t & 63) == 0) red4[t >> 6] = mx;
    __syncthreads();
    mx = fmaxf(fmaxf(red4[0], red4[1]), fmaxf(red4[2], red4[3]));
    __syncthreads();

    float e = expf(g - mx);
    float ssum = e;
    #pragma unroll
    for (int off = 32; off; off >>= 1) ssum += __shfl_xor(ssum, off);
    if ((t & 63) == 0) red4[t >> 6] = ssum;
    __syncthreads();
    ssum = red4[0] + red4[1] + red4[2] + red4[3];
    __syncthreads();

    float w = (e / ssum) * (float)mk;
    float s2 = w;
    #pragma unroll
    for (int off = 32; off; off >>= 1) s2 += __shfl_xor(s2, off);
    if ((t & 63) == 0) red4[t >> 6] = s2;
    __syncthreads();
    s2 = red4[0] + red4[1] + red4[2] + red4[3];
    __syncthreads();
    w = w / fmaxf(s2, 1e-8f);
    wS[t] = w;

    float cpart = tms[b * Mc + t] * w;
    #pragma unroll
    for (int off = 32; off; off >>= 1) cpart += __shfl_xor(cpart, off);
    if ((t & 63) == 0) red4[t >> 6] = cpart;
    __syncthreads();
    float contra = 1.0f - (red4[0] + red4[1] + red4[2] + red4[3]);
    __syncthreads();

    // grounding[b][t] = sum_m wS[m] * pairO[b,m,t]
    const float* P = pairO + (long long)b * Mc * Dc;
    float acc = 0.0f;
    for (int m = 0; m < Mc; m++) acc += wS[m] * P[(long long)m * Dc + t];
    grounding_out[b * Dc + t] = acc;
    featS[t] = acc * (1.0f + contra);
    __syncthreads();

    if (t < 128) {
        float a = bs1[t];
        for (int k = 0; k < Dc; k++) a += featS[k] * Ws1[k * 128 + t];
        hS[t] = gelu_exact(a) * Ws2[t];
    }
    __syncthreads();
    if (t == 0) {
        float sc = bs2[0];
        for (int k = 0; k < 128; k++) sc += hS[k];
        score_out[b] = 1.0f / (1.0f + expf(-sc));
    }
}

// ---------------------------------------------------------------------------
extern "C" void kernel_launch(void* const* d_in, const int* in_sizes, int n_in,
                              void* d_out, int out_size, void* d_ws, size_t ws_size,
                              hipStream_t stream) {
    const float* vis  = (const float*)d_in[0];
    const float* txt  = (const float*)d_in[1];
    const int*   mask = (const int*)d_in[2];
    const float* Wg1  = (const float*)d_in[3];
    const float* bg1  = (const float*)d_in[4];
    const float* Wg2  = (const float*)d_in[5];
    const float* bg2  = (const float*)d_in[6];
    const float* Wo1  = (const float*)d_in[7];
    const float* bo1  = (const float*)d_in[8];
    const float* ln_g = (const float*)d_in[9];
    const float* ln_b = (const float*)d_in[10];
    const float* Wo2  = (const float*)d_in[11];
    const float* bo2  = (const float*)d_in[12];
    const float* Ws1  = (const float*)d_in[13];
    const float* bs1  = (const float*)d_in[14];
    const float* Ws2  = (const float*)d_in[15];
    const float* bs2  = (const float*)d_in[16];

    float* out = (float*)d_out;
    float* o_sim    = out;                                  // B*M*N
    float* o_tms    = o_sim + (size_t)Bc * Mc * Nc;         // B*M
    float* o_idx    = o_tms + (size_t)Bc * Mc;              // B*M (float-cast idx)
    float* o_logits = o_idx + (size_t)Bc * Mc;              // B*M*2
    float* o_ground = o_logits + (size_t)Bc * Mc * 2;       // B*D
    float* o_score  = o_ground + (size_t)Bc * Dc;           // B
    float* o_wp     = o_score + (size_t)Bc;                 // B*N*D

    float* ws = (float*)d_ws;
    float* vis_n   = ws;                                    // B*N*D = 33,554,432
    float* txt_n   = vis_n + (size_t)Bc * Nc * Dc;          // B*M*D =  8,388,608
    float* pairbuf = txt_n + (size_t)Bc * Mc * Dc;          // B*M*2D = 16,777,216
    float* H1      = pairbuf + (size_t)Bc * Mc * 2 * Dc;    // B*M*D
    float* smallw  = H1 + (size_t)Bc * Mc * Dc;
    int*   idx_ws  = (int*)smallw;                          // B*M
    float* cmaxb   = smallw + Bc * Mc;                      // B*N
    float* crecipb = cmaxb + Bc * Nc;                       // B*N
    float* gateb   = crecipb + Bc * Nc;                     // B*M
    // pairbuf is dead after the Wo1 GEMM -> reuse for pairO and G
    float* pairO = pairbuf;
    float* Gb    = pairbuf + (size_t)Bc * Mc * Dc;

    // 1) normalize (163840 rows, wave per row, 4 waves/block)
    normalize_kernel<<<(Bc * Nc + Bc * Mc) / 4, 256, 0, stream>>>(vis, txt, vis_n, txt_n);
    // 2) sim GEMM
    simgemm_kernel<<<dim3(Nc / 64, Mc / 64, Bc), 256, 0, stream>>>(txt_n, vis_n, o_sim);
    // 3) row max/argmax, logits, mask sim
    rowstats_kernel<<<(Bc * Mc) / 4, 256, 0, stream>>>(o_sim, mask, o_tms, o_idx, o_logits, idx_ws);
    // 4) column softmax stats (over masked sim)
    colstats_kernel<<<dim3(Nc / 256, Bc), 256, 0, stream>>>(o_sim, cmaxb, crecipb);
    // 5) weighted_patch GEMM
    wpgemm_kernel<<<dim3(Dc / 64, Nc / 64, Bc), 256, 0, stream>>>(o_sim, txt_n, cmaxb, crecipb, o_wp);
    // 6) gather pair
    gatherpair_kernel<<<(Bc * Mc) / 4, 256, 0, stream>>>(txt_n, vis_n, idx_ws, pairbuf);
    // 7) pair @ Wo1 + bo1 -> H1
    gemmnn_kernel<0><<<dim3(Dc / 64, (Bc * Mc) / 64), 256, 0, stream>>>(pairbuf, Wo1, bo1, H1, Bc * Mc, 2 * Dc, Dc);
    // 8) LN + GELU in place
    lngelu_kernel<<<(Bc * Mc) / 4, 256, 0, stream>>>(H1, ln_g, ln_b);
    // 9) H1 @ Wo2 + bo2 -> pairO
    gemmnn_kernel<0><<<dim3(Dc / 64, (Bc * Mc) / 64), 256, 0, stream>>>(H1, Wo2, bo2, pairO, Bc * Mc, Dc, Dc);
    // 10) pairO @ Wg1 + bg1, GELU -> Gb
    gemmnn_kernel<1><<<dim3(Dc / 64, (Bc * Mc) / 64), 256, 0, stream>>>(pairO, Wg1, bg1, Gb, Bc * Mc, Dc, Dc);
    // 11) Gb @ Wg2 + bg2 -> gate
    gate_kernel<<<(Bc * Mc) / 4, 256, 0, stream>>>(Gb, Wg2, bg2, gateb);
    // 12) per-b softmax/grounding/score
    final_kernel<<<Bc, 256, 0, stream>>>(gateb, mask, o_tms, pairO, Ws1, bs1, Ws2, bs2, o_ground, o_score);
}

// Round 3
// 887.451 us; speedup vs baseline: 2.6082x; 2.6082x over previous
//
#include <hip/hip_runtime.h>
#include <math.h>

// Problem constants
static constexpr int Bc = 128;   // batch
static constexpr int Mc = 256;   // text tokens
static constexpr int Nc = 1024;  // patches
static constexpr int Dc = 256;   // dim

typedef __attribute__((ext_vector_type(8))) short bfrag;   // 8 bf16 (4 VGPR)
typedef __attribute__((ext_vector_type(4))) float f32x4;

__device__ __forceinline__ float gelu_exact(float x) {
    return 0.5f * x * (1.0f + erff(x * 0.70710678118654752440f));
}

// bf16 RNE convert (finite inputs only)
__device__ __forceinline__ unsigned short f2bf_rne(float x) {
    unsigned u = __builtin_bit_cast(unsigned, x);
    unsigned r = u + 0x7fffu + ((u >> 16) & 1u);
    return (unsigned short)(r >> 16);
}
__device__ __forceinline__ unsigned pk2(unsigned short a, unsigned short b) {
    return (unsigned)a | ((unsigned)b << 16);
}

// ---------------------------------------------------------------------------
// 1) L2-normalize rows of vis [B,N,D] and txt [B,M,D]; write plain bf16 rows
//    + inverse norms (for fp32 argmax refinement).  Wave per row.
__global__ void normalize_k(const float* __restrict__ vis,
                            const float* __restrict__ txt,
                            unsigned short* __restrict__ vis_b,
                            unsigned short* __restrict__ txt_b,
                            float* __restrict__ invv,
                            float* __restrict__ invt) {
    int wave = (blockIdx.x * blockDim.x + threadIdx.x) >> 6;
    int lane = threadIdx.x & 63;
    const int visRows = Bc * Nc;
    const float* src; unsigned short* dst; float* invp; long long row;
    if (wave < visRows) { src = vis; dst = vis_b; invp = invv; row = wave; }
    else { src = txt; dst = txt_b; invp = invt; row = wave - visRows; }
    float4 v = ((const float4*)(src + row * Dc))[lane];
    float ss = v.x * v.x + v.y * v.y + v.z * v.z + v.w * v.w;
    #pragma unroll
    for (int off = 32; off; off >>= 1) ss += __shfl_xor(ss, off);
    float sc = 1.0f / fmaxf(sqrtf(ss), 1e-8f);
    if (lane == 0) invp[row] = sc;
    unsigned short h0 = f2bf_rne(v.x * sc), h1 = f2bf_rne(v.y * sc);
    unsigned short h2 = f2bf_rne(v.z * sc), h3 = f2bf_rne(v.w * sc);
    *(uint2*)(dst + row * 256 + lane * 4) = make_uint2(pk2(h0, h1), pk2(h2, h3));
}

// ---------------------------------------------------------------------------
// 2) Transpose+convert fp32 weight W[R,C] -> Wt[C][R] bf16
__global__ __launch_bounds__(256) void tcvt(const float* __restrict__ W,
                                            unsigned short* __restrict__ Wt,
                                            int R, int Cdim) {
    __shared__ unsigned short T[64 * 72];
    int r0 = blockIdx.x * 64, c0 = blockIdx.y * 64;
    int t = threadIdx.x;
    int rl = t >> 4, c4 = (t & 15) << 2;
    #pragma unroll
    for (int i = 0; i < 4; i++) {
        int r = rl + i * 16;
        float4 v = *(const float4*)(W + (long long)(r0 + r) * Cdim + c0 + c4);
        T[(c4 + 0) * 72 + r] = f2bf_rne(v.x);
        T[(c4 + 1) * 72 + r] = f2bf_rne(v.y);
        T[(c4 + 2) * 72 + r] = f2bf_rne(v.z);
        T[(c4 + 3) * 72 + r] = f2bf_rne(v.w);
    }
    __syncthreads();
    #pragma unroll
    for (int i = 0; i < 2; i++) {
        int cc = i * 256 + t, cl = cc >> 3, seg = cc & 7;
        unsigned short sv[8];
        #pragma unroll
        for (int j = 0; j < 8; j++) sv[j] = T[cl * 72 + seg * 8 + j];
        *(uint4*)(Wt + (long long)(c0 + cl) * R + r0 + seg * 8) = *(uint4*)sv;
    }
}

// ---------------------------------------------------------------------------
// 3) Transpose bf16 txt_b [b][m][d] -> Tt [b][d][m]
__global__ __launch_bounds__(256) void t_txt(const unsigned short* __restrict__ txt_b,
                                             unsigned short* __restrict__ Tt) {
    __shared__ unsigned short T[64 * 72];
    int b = blockIdx.z;
    int m0 = blockIdx.x * 64, d0 = blockIdx.y * 64;
    const unsigned short* in = txt_b + (long long)b * 256 * 256;
    unsigned short* out = Tt + (long long)b * 256 * 256;
    int t = threadIdx.x;
    #pragma unroll
    for (int i = 0; i < 2; i++) {
        int cc = i * 256 + t, ml = cc >> 3, seg = cc & 7;
        uint4 v = *(const uint4*)(in + (long long)(m0 + ml) * 256 + d0 + seg * 8);
        unsigned short sv[8];
        *(uint4*)sv = v;
        #pragma unroll
        for (int j = 0; j < 8; j++) T[(seg * 8 + j) * 72 + ml] = sv[j];
    }
    __syncthreads();
    #pragma unroll
    for (int i = 0; i < 2; i++) {
        int cc = i * 256 + t, dl = cc >> 3, seg = cc & 7;
        unsigned short sv[8];
        #pragma unroll
        for (int j = 0; j < 8; j++) sv[j] = T[dl * 72 + seg * 8 + j];
        *(uint4*)(out + (long long)(d0 + dl) * 256 + m0 + seg * 8) = *(uint4*)sv;
    }
}

// ---------------------------------------------------------------------------
// 4) Generic NT bf16 MFMA GEMM: C[128y x 128x] = A[.,Ks] * B[.,Ks]^T
//    EPI: 0 plain, 1 +bias, 2 +bias +bf16-out, 3 +bias +gelu
template <int EPI>
__global__ __launch_bounds__(256) void gemm_nt(const unsigned short* __restrict__ A,
                                               const unsigned short* __restrict__ B,
                                               const float* __restrict__ bias,
                                               float* __restrict__ C,
                                               unsigned short* __restrict__ Cs,
                                               int Ks, int lda, int ldb, int ldc,
                                               long long sA, long long sB, long long sC) {
    __shared__ unsigned short As[128 * 64];
    __shared__ unsigned short Bs[128 * 64];
    int z = blockIdx.z;
    const unsigned short* Ab = A + (long long)z * sA + (long long)blockIdx.y * 128 * lda;
    const unsigned short* Bb = B + (long long)z * sB + (long long)blockIdx.x * 128 * ldb;
    int t = threadIdx.x;
    int lane = t & 63, wid = t >> 6;
    int wr = wid >> 1, wc = wid & 1;
    int lr = lane & 15, lk = lane >> 4;
    f32x4 acc[4][4];
    #pragma unroll
    for (int i = 0; i < 4; i++)
        #pragma unroll
        for (int j = 0; j < 4; j++) acc[i][j] = (f32x4){0.f, 0.f, 0.f, 0.f};

    for (int k0 = 0; k0 < Ks; k0 += 64) {
        uint4 va[4], vb[4];
        #pragma unroll
        for (int i = 0; i < 4; i++) {
            int c = i * 256 + t, row = c >> 3, kc = c & 7;
            va[i] = *(const uint4*)(Ab + (long long)row * lda + k0 + kc * 8);
            vb[i] = *(const uint4*)(Bb + (long long)row * ldb + k0 + kc * 8);
        }
        __syncthreads();   // previous iter's readers done before overwrite
        #pragma unroll
        for (int i = 0; i < 4; i++) {
            int c = i * 256 + t, row = c >> 3, kc = c & 7;
            int dst = row * 64 + ((kc ^ (row & 7)) << 3);   // XOR swizzle (G4)
            *(uint4*)(As + dst) = va[i];
            *(uint4*)(Bs + dst) = vb[i];
        }
        __syncthreads();
        #pragma unroll
        for (int ks = 0; ks < 2; ks++) {
            bfrag av[4], bv[4];
            #pragma unroll
            for (int f = 0; f < 4; f++) {
                int ra = wr * 64 + f * 16 + lr;
                av[f] = *(const bfrag*)(As + ra * 64 + ((((ks << 2) | lk) ^ (ra & 7)) << 3));
                int rb = wc * 64 + f * 16 + lr;
                bv[f] = *(const bfrag*)(Bs + rb * 64 + ((((ks << 2) | lk) ^ (rb & 7)) << 3));
            }
            #pragma unroll
            for (int fm = 0; fm < 4; fm++)
                #pragma unroll
                for (int fn = 0; fn < 4; fn++)
                    acc[fm][fn] = __builtin_amdgcn_mfma_f32_16x16x32_bf16(av[fm], bv[fn], acc[fm][fn], 0, 0, 0);
        }
    }

    long long cb = (long long)z * sC;
    int rbase = blockIdx.y * 128 + wr * 64;
    int cbase = blockIdx.x * 128 + wc * 64;
    #pragma unroll
    for (int fn = 0; fn < 4; fn++) {
        int col = cbase + fn * 16 + lr;
        float bv_ = (EPI > 0) ? bias[col] : 0.0f;
        #pragma unroll
        for (int fm = 0; fm < 4; fm++) {
            #pragma unroll
            for (int r = 0; r < 4; r++) {
                int row = rbase + fm * 16 + lk * 4 + r;
                float v = acc[fm][fn][r] + bv_;
                if (EPI == 3) v = gelu_exact(v);
                C[cb + (long long)row * ldc + col] = v;
                if (EPI == 2) Cs[(long long)row * ldc + col] = f2bf_rne(v);
            }
        }
    }
}

// ---------------------------------------------------------------------------
// 5) row max/argmax with fp32 candidate refinement; write tms/idx/logits;
//    mask sim rows to -1.  Wave per row, 4 waves/block (grid exact).
__global__ void rowstats_kernel(float* __restrict__ sim,
                                const int* __restrict__ mask,
                                const float* __restrict__ txt,
                                const float* __restrict__ vis,
                                const float* __restrict__ invt,
                                const float* __restrict__ invv,
                                float* __restrict__ tms_out,
                                float* __restrict__ idx_out,
                                float* __restrict__ logits_out,
                                int* __restrict__ idx_ws) {
    __shared__ int candS[4][64];
    __shared__ int cntS[4];
    int w = threadIdx.x >> 6, lane = threadIdx.x & 63;
    int row = blockIdx.x * 4 + w;
    float* srow = sim + (long long)row * Nc;
    float4 vals[4];
    float best = -3.0e38f;
    #pragma unroll
    for (int s = 0; s < 4; s++) {
        vals[s] = *(const float4*)(srow + s * 256 + lane * 4);
        best = fmaxf(best, fmaxf(fmaxf(vals[s].x, vals[s].y), fmaxf(vals[s].z, vals[s].w)));
    }
    #pragma unroll
    for (int off = 32; off; off >>= 1) best = fmaxf(best, __shfl_xor(best, off));
    if (lane == 0) cntS[w] = 0;
    __syncthreads();
    // bf16 GEMM absolute error bound ~1.4e-3 (max over 33.5M entries); pairwise
    // 2.8e-3 -> eps=4e-3 guarantees the true argmax is in the candidate set.
    float th = best - 4e-3f;
    #pragma unroll
    for (int s = 0; s < 4; s++) {
        int base = s * 256 + lane * 4;
        float4 v = vals[s];
        if (v.x >= th) { int sl = atomicAdd(&cntS[w], 1); if (sl < 64) candS[w][sl] = base; }
        if (v.y >= th) { int sl = atomicAdd(&cntS[w], 1); if (sl < 64) candS[w][sl] = base + 1; }
        if (v.z >= th) { int sl = atomicAdd(&cntS[w], 1); if (sl < 64) candS[w][sl] = base + 2; }
        if (v.w >= th) { int sl = atomicAdd(&cntS[w], 1); if (sl < 64) candS[w][sl] = base + 3; }
    }
    __syncthreads();
    int cnt = min(cntS[w], 64);
    int b = row >> 8;
    int bi = candS[w][0];
    if (cnt > 1) {
        // fp32 re-score: dot(txt_raw, vis_raw) * invt * invv, first-index tie-break
        float4 t4 = ((const float4*)(txt + (long long)row * Dc))[lane];
        float it = invt[row];
        float bestv = -3.0e38f; bi = 1 << 30;
        for (int c = 0; c < cnt; c++) {
            int n = candS[w][c];
            float4 v4 = ((const float4*)(vis + ((long long)b * Nc + n) * Dc))[lane];
            float d = t4.x * v4.x + t4.y * v4.y + t4.z * v4.z + t4.w * v4.w;
            #pragma unroll
            for (int off = 32; off; off >>= 1) d += __shfl_xor(d, off);
            float val = d * it * invv[b * Nc + n];
            if (val > bestv || (val == bestv && n < bi)) { bestv = val; bi = n; }
        }
    }
    int mk = mask[row];
    if (lane == 0) {
        float tms = mk ? best : 0.0f;
        tms_out[row] = tms;
        idx_out[row] = (float)bi;
        idx_ws[row] = bi;
        float pf = fminf(fmaxf(tms, 0.0f), 1.0f);
        logits_out[row * 2 + 0] = 1.0f - pf;
        logits_out[row * 2 + 1] = pf;
    }
    if (mk == 0) {
        float4 mv = make_float4(-1.0f, -1.0f, -1.0f, -1.0f);
        #pragma unroll
        for (int s = 0; s < 4; s++) *(float4*)(srow + s * 256 + lane * 4) = mv;
    }
}

// ---------------------------------------------------------------------------
// 6) column softmax stats over m (masked sim): cmax[b,n], crecip[b,n]
__global__ void colstats_kernel(const float* __restrict__ sim,
                                float* __restrict__ cmax,
                                float* __restrict__ crecip) {
    int b = blockIdx.y;
    int n = blockIdx.x * 256 + threadIdx.x;
    const float* base = sim + (long long)b * Mc * Nc + n;
    float mx = -3.0e38f;
    for (int m = 0; m < Mc; m++) mx = fmaxf(mx, base[(long long)m * Nc]);
    float s = 0.0f;
    for (int m = 0; m < Mc; m++) s += expf(base[(long long)m * Nc] - mx);
    cmax[b * Nc + n] = mx;
    crecip[b * Nc + n] = 1.0f / s;
}

// ---------------------------------------------------------------------------
// 7) weighted_patch MFMA GEMM: C[n][d] = sum_m P[n][m]*txt[m][d]
//    A staged in-kernel from sim (exp+cvt), B = Tt [d][m]
__global__ __launch_bounds__(256) void wp_gemm(const float* __restrict__ sim,
                                               const unsigned short* __restrict__ Tt,
                                               const float* __restrict__ cmax,
                                               const float* __restrict__ crecip,
                                               float* __restrict__ wpout) {
    __shared__ unsigned short As[128 * 64];
    __shared__ unsigned short Bs[128 * 64];
    int z = blockIdx.z;
    const float* S = sim + (long long)z * Mc * Nc;
    const unsigned short* Bb = Tt + (long long)z * 256 * 256 + (long long)blockIdx.x * 128 * 256;
    int n0 = blockIdx.y * 128;
    int t = threadIdx.x;
    int lane = t & 63, wid = t >> 6, wr = wid >> 1, wc = wid & 1;
    int lr = lane & 15, lk = lane >> 4;
    int nl = t & 127, mh = t >> 7;
    float cm = cmax[(long long)z * Nc + n0 + nl];
    float cr = crecip[(long long)z * Nc + n0 + nl];
    f32x4 acc[4][4];
    #pragma unroll
    for (int i = 0; i < 4; i++)
        #pragma unroll
        for (int j = 0; j < 4; j++) acc[i][j] = (f32x4){0.f, 0.f, 0.f, 0.f};

    for (int g = 0; g < 4; g++) {   // 4 m-blocks of 64
        uint4 vb[4];
        #pragma unroll
        for (int i = 0; i < 4; i++) {
            int c = i * 256 + t, row = c >> 3, kc = c & 7;
            vb[i] = *(const uint4*)(Bb + (long long)row * 256 + g * 64 + kc * 8);
        }
        unsigned short pv[32];
        #pragma unroll
        for (int j = 0; j < 32; j++) {
            int m = g * 64 + mh * 32 + j;
            float v = S[(long long)m * Nc + n0 + nl];
            pv[j] = f2bf_rne(expf(v - cm) * cr);
        }
        __syncthreads();
        #pragma unroll
        for (int i = 0; i < 4; i++) {
            int c = i * 256 + t, row = c >> 3, kc = c & 7;
            *(uint4*)(Bs + row * 64 + ((kc ^ (row & 7)) << 3)) = vb[i];
        }
        #pragma unroll
        for (int q = 0; q < 4; q++) {
            uint4 h = make_uint4(pk2(pv[q * 8 + 0], pv[q * 8 + 1]), pk2(pv[q * 8 + 2], pv[q * 8 + 3]),
                                 pk2(pv[q * 8 + 4], pv[q * 8 + 5]), pk2(pv[q * 8 + 6], pv[q * 8 + 7]));
            *(uint4*)(As + nl * 64 + (((mh * 4 + q) ^ (nl & 7)) << 3)) = h;
        }
        __syncthreads();
        #pragma unroll
        for (int ks = 0; ks < 2; ks++) {
            bfrag av[4], bv2[4];
            #pragma unroll
            for (int f = 0; f < 4; f++) {
                int ra = wr * 64 + f * 16 + lr;
                av[f] = *(const bfrag*)(As + ra * 64 + ((((ks << 2) | lk) ^ (ra & 7)) << 3));
                int rb = wc * 64 + f * 16 + lr;
                bv2[f] = *(const bfrag*)(Bs + rb * 64 + ((((ks << 2) | lk) ^ (rb & 7)) << 3));
            }
            #pragma unroll
            for (int fm = 0; fm < 4; fm++)
                #pragma unroll
                for (int fn = 0; fn < 4; fn++)
                    acc[fm][fn] = __builtin_amdgcn_mfma_f32_16x16x32_bf16(av[fm], bv2[fn], acc[fm][fn], 0, 0, 0);
        }
        __syncthreads();   // before next iter's LDS overwrite
    }

    float* C = wpout + (long long)z * Nc * Dc;
    int rbase = n0 + wr * 64;
    int cbase = blockIdx.x * 128 + wc * 64;
    #pragma unroll
    for (int fn = 0; fn < 4; fn++) {
        int col = cbase + fn * 16 + lr;
        #pragma unroll
        for (int fm = 0; fm < 4; fm++) {
            #pragma unroll
            for (int r = 0; r < 4; r++) {
                int row = rbase + fm * 16 + lk * 4 + r;
                C[(long long)row * Dc + col] = acc[fm][fn][r];
            }
        }
    }
}

// ---------------------------------------------------------------------------
// 8) pair_b[m] = [txt_b row | vis_b gathered row]  (wave per row)
__global__ void gatherpair_k(const unsigned short* __restrict__ txt_b,
                             const unsigned short* __restrict__ vis_b,
                             const int* __restrict__ idx_ws,
                             unsigned short* __restrict__ pair_b) {
    int wave = (blockIdx.x * blockDim.x + threadIdx.x) >> 6;
    int lane = threadIdx.x & 63;
    int b = wave >> 8;      // / Mc
    int bi = idx_ws[wave];
    int half = lane >> 5, c = lane & 31;
    const unsigned short* srcrow = half ? (vis_b + ((long long)b * Nc + bi) * 256)
                                        : (txt_b + (long long)wave * 256);
    uint4 v = *(const uint4*)(srcrow + c * 8);
    *(uint4*)(pair_b + (long long)wave * 512 + half * 256 + c * 8) = v;
}

// ---------------------------------------------------------------------------
// 9) LayerNorm + GELU: read H fp32, write bf16 H_b
__global__ void lngelu_k(const float* __restrict__ H,
                         unsigned short* __restrict__ Hb,
                         const float* __restrict__ g,
                         const float* __restrict__ bta) {
    int wave = (blockIdx.x * blockDim.x + threadIdx.x) >> 6;
    int lane = threadIdx.x & 63;
    float4 v = ((const float4*)(H + (long long)wave * Dc))[lane];
    float s = v.x + v.y + v.z + v.w;
    #pragma unroll
    for (int off = 32; off; off >>= 1) s += __shfl_xor(s, off);
    float mu = s * (1.0f / 256.0f);
    float dx = v.x - mu, dy = v.y - mu, dz = v.z - mu, dw = v.w - mu;
    float ss = dx * dx + dy * dy + dz * dz + dw * dw;
    #pragma unroll
    for (int off = 32; off; off >>= 1) ss += __shfl_xor(ss, off);
    float rstd = 1.0f / sqrtf(ss * (1.0f / 256.0f) + 1e-5f);
    float4 G4 = ((const float4*)g)[lane];
    float4 B4 = ((const float4*)bta)[lane];
    unsigned short h0 = f2bf_rne(gelu_exact(dx * rstd * G4.x + B4.x));
    unsigned short h1 = f2bf_rne(gelu_exact(dy * rstd * G4.y + B4.y));
    unsigned short h2 = f2bf_rne(gelu_exact(dz * rstd * G4.z + B4.z));
    unsigned short h3 = f2bf_rne(gelu_exact(dw * rstd * G4.w + B4.w));
    *(uint2*)(Hb + (long long)wave * 256 + lane * 4) = make_uint2(pk2(h0, h1), pk2(h2, h3));
}

// ---------------------------------------------------------------------------
// 10) gate_raw[b,m] = G[b,m,:] . Wg2 + bg2   (wave per row, fp32)
__global__ void gate_kernel(const float* __restrict__ G,
                            const float* __restrict__ Wg2,
                            const float* __restrict__ bg2,
                            float* __restrict__ gate) {
    int wave = (blockIdx.x * blockDim.x + threadIdx.x) >> 6;
    int lane = threadIdx.x & 63;
    float4 v = ((const float4*)(G + (long long)wave * Dc))[lane];
    float4 w = ((const float4*)Wg2)[lane];
    float s = v.x * w.x + v.y * w.y + v.z * w.z + v.w * w.w;
    #pragma unroll
    for (int off = 32; off; off >>= 1) s += __shfl_xor(s, off);
    if (lane == 0) gate[wave] = s + bg2[0];
}

// ---------------------------------------------------------------------------
// 11) per-b: gate softmax, grounding, contradiction, score MLP (256 thr/block)
__global__ __launch_bounds__(256) void final_kernel(const float* __restrict__ gate,
                                                    const int* __restrict__ mask,
                                                    const float* __restrict__ tms,
                                                    const float* __restrict__ pairO,
                                                    const float* __restrict__ Ws1,
                                                    const float* __restrict__ bs1,
                                                    const float* __restrict__ Ws2,
                                                    const float* __restrict__ bs2,
                                                    float* __restrict__ grounding_out,
                                                    float* __restrict__ score_out) {
    __shared__ float wS[256];
    __shared__ float featS[256];
    __shared__ float hS[128];
    __shared__ float red4[4];
    int b = blockIdx.x, t = threadIdx.x;
    int mk = mask[b * Mc + t];
    float g = mk ? gate[b * Mc + t] : -10000.0f;

    float mx = g;
    #pragma unroll
    for (int off = 32; off; off >>= 1) mx = fmaxf(mx, __shfl_xor(mx, off));
    if ((t & 63) == 0) red4[t >> 6] = mx;
    __syncthreads();
    mx = fmaxf(fmaxf(red4[0], red4[1]), fmaxf(red4[2], red4[3]));
    __syncthreads();

    float e = expf(g - mx);
    float ssum = e;
    #pragma unroll
    for (int off = 32; off; off >>= 1) ssum += __shfl_xor(ssum, off);
    if ((t & 63) == 0) red4[t >> 6] = ssum;
    __syncthreads();
    ssum = red4[0] + red4[1] + red4[2] + red4[3];
    __syncthreads();

    float w = (e / ssum) * (float)mk;
    float s2 = w;
    #pragma unroll
    for (int off = 32; off; off >>= 1) s2 += __shfl_xor(s2, off);
    if ((t & 63) == 0) red4[t >> 6] = s2;
    __syncthreads();
    s2 = red4[0] + red4[1] + red4[2] + red4[3];
    __syncthreads();
    w = w / fmaxf(s2, 1e-8f);
    wS[t] = w;

    float cpart = tms[b * Mc + t] * w;
    #pragma unroll
    for (int off = 32; off; off >>= 1) cpart += __shfl_xor(cpart, off);
    if ((t & 63) == 0) red4[t >> 6] = cpart;
    __syncthreads();
    float contra = 1.0f - (red4[0] + red4[1] + red4[2] + red4[3]);
    __syncthreads();

    const float* P = pairO + (long long)b * Mc * Dc;
    float acc = 0.0f;
    for (int m = 0; m < Mc; m++) acc += wS[m] * P[(long long)m * Dc + t];
    grounding_out[b * Dc + t] = acc;
    featS[t] = acc * (1.0f + contra);
    __syncthreads();

    if (t < 128) {
        float a = bs1[t];
        for (int k = 0; k < Dc; k++) a += featS[k] * Ws1[k * 128 + t];
        hS[t] = gelu_exact(a) * Ws2[t];
    }
    __syncthreads();
    if (t == 0) {
        float sc = bs2[0];
        for (int k = 0; k < 128; k++) sc += hS[k];
        score_out[b] = 1.0f / (1.0f + expf(-sc));
    }
}

// ---------------------------------------------------------------------------
extern "C" void kernel_launch(void* const* d_in, const int* in_sizes, int n_in,
                              void* d_out, int out_size, void* d_ws, size_t ws_size,
                              hipStream_t stream) {
    const float* vis  = (const float*)d_in[0];
    const float* txt  = (const float*)d_in[1];
    const int*   mask = (const int*)d_in[2];
    const float* Wg1  = (const float*)d_in[3];
    const float* bg1  = (const float*)d_in[4];
    const float* Wg2  = (const float*)d_in[5];
    const float* bg2  = (const float*)d_in[6];
    const float* Wo1  = (const float*)d_in[7];
    const float* bo1  = (const float*)d_in[8];
    const float* ln_g = (const float*)d_in[9];
    const float* ln_b = (const float*)d_in[10];
    const float* Wo2  = (const float*)d_in[11];
    const float* bo2  = (const float*)d_in[12];
    const float* Ws1  = (const float*)d_in[13];
    const float* bs1  = (const float*)d_in[14];
    const float* Ws2  = (const float*)d_in[15];
    const float* bs2  = (const float*)d_in[16];

    float* out = (float*)d_out;
    float* o_sim    = out;                                  // B*M*N
    float* o_tms    = o_sim + (size_t)Bc * Mc * Nc;
    float* o_idx    = o_tms + (size_t)Bc * Mc;
    float* o_logits = o_idx + (size_t)Bc * Mc;
    float* o_ground = o_logits + (size_t)Bc * Mc * 2;
    float* o_score  = o_ground + (size_t)Bc * Dc;
    float* o_wp     = o_score + (size_t)Bc;                 // B*N*D

    // Workspace layout — fully disjoint (no aliasing):
    char* wsb = (char*)d_ws;
    unsigned short* vis_b  = (unsigned short*)(wsb + 0);           // 67,108,864 B
    unsigned short* txt_b  = (unsigned short*)(wsb + 67108864);    // 16,777,216
    unsigned short* Tt     = (unsigned short*)(wsb + 83886080);    // 16,777,216
    unsigned short* pair_b = (unsigned short*)(wsb + 100663296);   // 33,554,432
    float*          H1     = (float*)(wsb + 134217728);            // 33,554,432
    unsigned short* H1_b   = (unsigned short*)(wsb + 167772160);   // 16,777,216
    float*          pairO  = (float*)(wsb + 184549376);            // 33,554,432
    unsigned short* pairO_b= (unsigned short*)(wsb + 218103808);   // 16,777,216
    float*          Gb     = (float*)(wsb + 234881024);            // 33,554,432
    char* sm = wsb + 268435456;
    float* invv    = (float*)(sm + 0);              // 524288
    float* invt    = (float*)(sm + 524288);         // 131072
    float* cmaxb   = (float*)(sm + 655360);         // 524288
    float* crecipb = (float*)(sm + 1179648);        // 524288
    int*   idx_ws  = (int*)(sm + 1703936);          // 131072
    float* gateb   = (float*)(sm + 1835008);        // 131072
    unsigned short* Wo1_t = (unsigned short*)(sm + 1966080);  // 262144
    unsigned short* Wo2_t = (unsigned short*)(sm + 2228224);  // 131072
    unsigned short* Wg1_t = (unsigned short*)(sm + 2359296);  // 131072

    // 1) normalize + bf16 convert + inv norms
    normalize_k<<<(Bc * Nc + Bc * Mc) / 4, 256, 0, stream>>>(vis, txt, vis_b, txt_b, invv, invt);
    // 2) weight transposes (bf16)
    tcvt<<<dim3(8, 4), 256, 0, stream>>>(Wo1, Wo1_t, 512, 256);
    tcvt<<<dim3(4, 4), 256, 0, stream>>>(Wo2, Wo2_t, 256, 256);
    tcvt<<<dim3(4, 4), 256, 0, stream>>>(Wg1, Wg1_t, 256, 256);
    // 3) sim = txt_n @ vis_n^T  (MFMA bf16, K=256)
    gemm_nt<0><<<dim3(8, 2, 128), 256, 0, stream>>>(txt_b, vis_b, nullptr, o_sim, nullptr,
                                                    256, 256, 256, 1024,
                                                    256LL * 256, 1024LL * 256, 256LL * 1024);
    // 4) row stats + fp32 argmax refinement + mask sim
    rowstats_kernel<<<(Bc * Mc) / 4, 256, 0, stream>>>(o_sim, mask, txt, vis, invt, invv,
                                                       o_tms, o_idx, o_logits, idx_ws);
    // 5) column softmax stats
    colstats_kernel<<<dim3(Nc / 256, Bc), 256, 0, stream>>>(o_sim, cmaxb, crecipb);
    // 6) txt transpose for wp B-operand
    t_txt<<<dim3(4, 4, 128), 256, 0, stream>>>(txt_b, Tt);
    // 7) weighted_patch (MFMA)
    wp_gemm<<<dim3(2, 8, 128), 256, 0, stream>>>(o_sim, Tt, cmaxb, crecipb, o_wp);
    // 8) gather pair
    gatherpair_k<<<(Bc * Mc) / 4, 256, 0, stream>>>(txt_b, vis_b, idx_ws, pair_b);
    // 9) H1 = pair @ Wo1 + bo1  (K=512)
    gemm_nt<1><<<dim3(2, 256, 1), 256, 0, stream>>>(pair_b, Wo1_t, bo1, H1, nullptr,
                                                    512, 512, 512, 256, 0, 0, 0);
    // 10) LN + GELU -> H1_b
    lngelu_k<<<(Bc * Mc) / 4, 256, 0, stream>>>(H1, H1_b, ln_g, ln_b);
    // 11) pairO = H1 @ Wo2 + bo2 (f32 + bf16 out)
    gemm_nt<2><<<dim3(2, 256, 1), 256, 0, stream>>>(H1_b, Wo2_t, bo2, pairO, pairO_b,
                                                    256, 256, 256, 256, 0, 0, 0);
    // 12) Gb = gelu(pairO @ Wg1 + bg1)
    gemm_nt<3><<<dim3(2, 256, 1), 256, 0, stream>>>(pairO_b, Wg1_t, bg1, Gb, nullptr,
                                                    256, 256, 256, 256, 0, 0, 0);
    // 13) gate
    gate_kernel<<<(Bc * Mc) / 4, 256, 0, stream>>>(Gb, Wg2, bg2, gateb);
    // 14) finale
    final_kernel<<<Bc, 256, 0, stream>>>(gateb, mask, o_tms, pairO, Ws1, bs1, Ws2, bs2, o_ground, o_score);
}

// Round 5
// 753.577 us; speedup vs baseline: 3.0716x; 1.1777x over previous
//
#include <hip/hip_runtime.h>
#include <math.h>

// Problem constants
static constexpr int Bc = 128;   // batch
static constexpr int Mc = 256;   // text tokens
static constexpr int Nc = 1024;  // patches
static constexpr int Dc = 256;   // dim

typedef __attribute__((ext_vector_type(8))) short bfrag;   // 8 bf16 (4 VGPR)
typedef __attribute__((ext_vector_type(4))) float f32x4;

__device__ __forceinline__ float gelu_exact(float x) {
    return 0.5f * x * (1.0f + erff(x * 0.70710678118654752440f));
}

// bf16 RNE convert (finite inputs only)
__device__ __forceinline__ unsigned short f2bf_rne(float x) {
    unsigned u = __builtin_bit_cast(unsigned, x);
    unsigned r = u + 0x7fffu + ((u >> 16) & 1u);
    return (unsigned short)(r >> 16);
}
__device__ __forceinline__ unsigned pk2(unsigned short a, unsigned short b) {
    return (unsigned)a | ((unsigned)b << 16);
}

// async global->LDS, 16B per lane. LDS dest is wave-uniform base (+lane*16);
// global src is per-lane (pre-swizzled source pattern, guide §5/m173).
// NOTE: direct C-style casts -> proper addrspacecast (no integer truncation).
__device__ __forceinline__ void gld16(const unsigned short* g, unsigned short* l) {
    __builtin_amdgcn_global_load_lds(
        (const __attribute__((address_space(1))) unsigned int*)g,
        (__attribute__((address_space(3))) unsigned int*)l,
        16, 0, 0);
}

// ---------------------------------------------------------------------------
// 1) L2-normalize rows of vis [B,N,D] and txt [B,M,D]; write plain bf16 rows
//    + inverse norms (for fp32 argmax refinement).  Wave per row.
__global__ void normalize_k(const float* __restrict__ vis,
                            const float* __restrict__ txt,
                            unsigned short* __restrict__ vis_b,
                            unsigned short* __restrict__ txt_b,
                            float* __restrict__ invv,
                            float* __restrict__ invt) {
    int wave = (blockIdx.x * blockDim.x + threadIdx.x) >> 6;
    int lane = threadIdx.x & 63;
    const int visRows = Bc * Nc;
    const float* src; unsigned short* dst; float* invp; long long row;
    if (wave < visRows) { src = vis; dst = vis_b; invp = invv; row = wave; }
    else { src = txt; dst = txt_b; invp = invt; row = wave - visRows; }
    float4 v = ((const float4*)(src + row * Dc))[lane];
    float ss = v.x * v.x + v.y * v.y + v.z * v.z + v.w * v.w;
    #pragma unroll
    for (int off = 32; off; off >>= 1) ss += __shfl_xor(ss, off);
    float sc = 1.0f / fmaxf(sqrtf(ss), 1e-8f);
    if (lane == 0) invp[row] = sc;
    unsigned short h0 = f2bf_rne(v.x * sc), h1 = f2bf_rne(v.y * sc);
    unsigned short h2 = f2bf_rne(v.z * sc), h3 = f2bf_rne(v.w * sc);
    *(uint2*)(dst + row * 256 + lane * 4) = make_uint2(pk2(h0, h1), pk2(h2, h3));
}

// ---------------------------------------------------------------------------
// 2) prep kernel: fused weight transpose+cvt for Wo1/Wo2/Wg1 + gate init to bg2
__device__ __forceinline__ void tile_tcvt(const float* W, unsigned short* Wt,
                                          int R, int Cdim, int rt, int ct,
                                          unsigned short* T) {
    int r0 = rt * 64, c0 = ct * 64;
    int t = threadIdx.x;
    int rl = t >> 4, c4 = (t & 15) << 2;
    #pragma unroll
    for (int i = 0; i < 4; i++) {
        int r = rl + i * 16;
        float4 v = *(const float4*)(W + (long long)(r0 + r) * Cdim + c0 + c4);
        T[(c4 + 0) * 72 + r] = f2bf_rne(v.x);
        T[(c4 + 1) * 72 + r] = f2bf_rne(v.y);
        T[(c4 + 2) * 72 + r] = f2bf_rne(v.z);
        T[(c4 + 3) * 72 + r] = f2bf_rne(v.w);
    }
    __syncthreads();
    #pragma unroll
    for (int i = 0; i < 2; i++) {
        int cc = i * 256 + t, cl = cc >> 3, seg = cc & 7;
        unsigned short sv[8];
        #pragma unroll
        for (int j = 0; j < 8; j++) sv[j] = T[cl * 72 + seg * 8 + j];
        *(uint4*)(Wt + (long long)(c0 + cl) * R + r0 + seg * 8) = *(uint4*)sv;
    }
}

__global__ __launch_bounds__(256) void prep_k(const float* __restrict__ Wo1,
                                              const float* __restrict__ Wo2,
                                              const float* __restrict__ Wg1,
                                              unsigned short* __restrict__ Wo1_t,
                                              unsigned short* __restrict__ Wo2_t,
                                              unsigned short* __restrict__ Wg1_t,
                                              const float* __restrict__ bg2,
                                              float* __restrict__ gateb) {
    __shared__ unsigned short T[64 * 72];
    int job = blockIdx.x;
    if (job < 32)      tile_tcvt(Wo1, Wo1_t, 512, 256, job >> 2, job & 3, T);
    else if (job < 48) tile_tcvt(Wo2, Wo2_t, 256, 256, (job - 32) >> 2, (job - 32) & 3, T);
    else if (job < 64) tile_tcvt(Wg1, Wg1_t, 256, 256, (job - 48) >> 2, (job - 48) & 3, T);
    else {
        float v = bg2[0];
        int base = (job - 64) * 8192 + threadIdx.x;
        #pragma unroll
        for (int i = 0; i < 32; i++) gateb[base + i * 256] = v;
    }
}

// ---------------------------------------------------------------------------
// 3) Transpose bf16 txt_b [b][m][d] -> Tt [b][d][m]
__global__ __launch_bounds__(256) void t_txt(const unsigned short* __restrict__ txt_b,
                                             unsigned short* __restrict__ Tt) {
    __shared__ unsigned short T[64 * 72];
    int b = blockIdx.z;
    int m0 = blockIdx.x * 64, d0 = blockIdx.y * 64;
    const unsigned short* in = txt_b + (long long)b * 256 * 256;
    unsigned short* out = Tt + (long long)b * 256 * 256;
    int t = threadIdx.x;
    #pragma unroll
    for (int i = 0; i < 2; i++) {
        int cc = i * 256 + t, ml = cc >> 3, seg = cc & 7;
        uint4 v = *(const uint4*)(in + (long long)(m0 + ml) * 256 + d0 + seg * 8);
        unsigned short sv[8];
        *(uint4*)sv = v;
        #pragma unroll
        for (int j = 0; j < 8; j++) T[(seg * 8 + j) * 72 + ml] = sv[j];
    }
    __syncthreads();
    #pragma unroll
    for (int i = 0; i < 2; i++) {
        int cc = i * 256 + t, dl = cc >> 3, seg = cc & 7;
        unsigned short sv[8];
        #pragma unroll
        for (int j = 0; j < 8; j++) sv[j] = T[dl * 72 + seg * 8 + j];
        *(uint4*)(out + (long long)(d0 + dl) * 256 + m0 + seg * 8) = *(uint4*)sv;
    }
}

// ---------------------------------------------------------------------------
// 4) Generic NT bf16 MFMA GEMM: C[128y x 128x] = A[.,Ks] * B[.,Ks]^T
//    Staging via global_load_lds (linear LDS dest + inverse-swizzled source).
//    EPI: 0 plain, 1 +bias, 2 +bias +bf16-out, 3 +bias +gelu,
//         4 +bias +gelu, fused dot with wg2 -> atomicAdd gate (no C write)
template <int EPI>
__global__ __launch_bounds__(256) void gemm_nt(const unsigned short* __restrict__ A,
                                               const unsigned short* __restrict__ B,
                                               const float* __restrict__ bias,
                                               float* __restrict__ C,
                                               unsigned short* __restrict__ Cs,
                                               const float* __restrict__ wg2,
                                               float* __restrict__ gateo,
                                               int Ks, int lda, int ldb, int ldc,
                                               long long sA, long long sB, long long sC) {
    __shared__ unsigned short As[128 * 64];
    __shared__ unsigned short Bs[128 * 64];
    int z = blockIdx.z;
    const unsigned short* Ab = A + (long long)z * sA + (long long)blockIdx.y * 128 * lda;
    const unsigned short* Bb = B + (long long)z * sB + (long long)blockIdx.x * 128 * ldb;
    int t = threadIdx.x;
    int lane = t & 63, wid = t >> 6;
    int wr = wid >> 1, wc = wid & 1;
    int lr = lane & 15, lk = lane >> 4;
    f32x4 acc[4][4];
    #pragma unroll
    for (int i = 0; i < 4; i++)
        #pragma unroll
        for (int j = 0; j < 4; j++) acc[i][j] = (f32x4){0.f, 0.f, 0.f, 0.f};

    for (int k0 = 0; k0 < Ks; k0 += 64) {
        __syncthreads();   // previous iter's LDS readers done before overwrite
        #pragma unroll
        for (int i = 0; i < 4; i++) {
            int wb = i * 256 + (t & 192);    // wave-uniform chunk base
            int c  = wb + (t & 63);
            int row = c >> 3, p = c & 7;
            int sw = (p ^ (row & 7)) << 3;   // inverse-swizzled source column
            gld16(Ab + (long long)row * lda + k0 + sw, As + wb * 8);
            gld16(Bb + (long long)row * ldb + k0 + sw, Bs + wb * 8);
        }
        __syncthreads();   // drains vmcnt -> tiles resident
        #pragma unroll
        for (int ks = 0; ks < 2; ks++) {
            bfrag av[4], bv[4];
            #pragma unroll
            for (int f = 0; f < 4; f++) {
                int ra = wr * 64 + f * 16 + lr;
                av[f] = *(const bfrag*)(As + ra * 64 + ((((ks << 2) | lk) ^ (ra & 7)) << 3));
                int rb = wc * 64 + f * 16 + lr;
                bv[f] = *(const bfrag*)(Bs + rb * 64 + ((((ks << 2) | lk) ^ (rb & 7)) << 3));
            }
            #pragma unroll
            for (int fm = 0; fm < 4; fm++)
                #pragma unroll
                for (int fn = 0; fn < 4; fn++)
                    acc[fm][fn] = __builtin_amdgcn_mfma_f32_16x16x32_bf16(av[fm], bv[fn], acc[fm][fn], 0, 0, 0);
        }
    }

    int rbase = blockIdx.y * 128 + wr * 64;
    int cbase = blockIdx.x * 128 + wc * 64;
    if constexpr (EPI == 4) {
        float part[4][4] = {};
        #pragma unroll
        for (int fn = 0; fn < 4; fn++) {
            int col = cbase + fn * 16 + lr;
            float bv_ = bias[col];
            float w2 = wg2[col];
            #pragma unroll
            for (int fm = 0; fm < 4; fm++)
                #pragma unroll
                for (int r = 0; r < 4; r++)
                    part[fm][r] += gelu_exact(acc[fm][fn][r] + bv_) * w2;
        }
        #pragma unroll
        for (int fm = 0; fm < 4; fm++)
            #pragma unroll
            for (int r = 0; r < 4; r++) {
                float p = part[fm][r];
                p += __shfl_xor(p, 1); p += __shfl_xor(p, 2);
                p += __shfl_xor(p, 4); p += __shfl_xor(p, 8);
                if (lr == 0) atomicAdd(&gateo[rbase + fm * 16 + lk * 4 + r], p);
            }
    } else {
        long long cb = (long long)z * sC;
        #pragma unroll
        for (int fn = 0; fn < 4; fn++) {
            int col = cbase + fn * 16 + lr;
            float bv_ = (EPI > 0) ? bias[col] : 0.0f;
            #pragma unroll
            for (int fm = 0; fm < 4; fm++) {
                #pragma unroll
                for (int r = 0; r < 4; r++) {
                    int row = rbase + fm * 16 + lk * 4 + r;
                    float v = acc[fm][fn][r] + bv_;
                    if (EPI == 3) v = gelu_exact(v);
                    C[cb + (long long)row * ldc + col] = v;
                    if (EPI == 2) Cs[(long long)row * ldc + col] = f2bf_rne(v);
                }
            }
        }
    }
}

// ---------------------------------------------------------------------------
// 5) row max/argmax with fp32 candidate refinement; write tms/idx/logits;
//    mask sim rows to -1.  Wave per row, 4 waves/block.
__global__ void rowstats_kernel(float* __restrict__ sim,
                                const int* __restrict__ mask,
                                const float* __restrict__ txt,
                                const float* __restrict__ vis,
                                const float* __restrict__ invt,
                                const float* __restrict__ invv,
                                float* __restrict__ tms_out,
                                float* __restrict__ idx_out,
                                float* __restrict__ logits_out,
                                int* __restrict__ idx_ws) {
    __shared__ int candS[4][64];
    __shared__ int cntS[4];
    int w = threadIdx.x >> 6, lane = threadIdx.x & 63;
    int row = blockIdx.x * 4 + w;
    float* srow = sim + (long long)row * Nc;
    float4 vals[4];
    float best = -3.0e38f;
    #pragma unroll
    for (int s = 0; s < 4; s++) {
        vals[s] = *(const float4*)(srow + s * 256 + lane * 4);
        best = fmaxf(best, fmaxf(fmaxf(vals[s].x, vals[s].y), fmaxf(vals[s].z, vals[s].w)));
    }
    #pragma unroll
    for (int off = 32; off; off >>= 1) best = fmaxf(best, __shfl_xor(best, off));
    if (lane == 0) cntS[w] = 0;
    __syncthreads();
    // bf16 GEMM abs error bound ~1.4e-3; pairwise 2.8e-3 -> eps=4e-3 covers true argmax.
    float th = best - 4e-3f;
    #pragma unroll
    for (int s = 0; s < 4; s++) {
        int base = s * 256 + lane * 4;
        float4 v = vals[s];
        if (v.x >= th) { int sl = atomicAdd(&cntS[w], 1); if (sl < 64) candS[w][sl] = base; }
        if (v.y >= th) { int sl = atomicAdd(&cntS[w], 1); if (sl < 64) candS[w][sl] = base + 1; }
        if (v.z >= th) { int sl = atomicAdd(&cntS[w], 1); if (sl < 64) candS[w][sl] = base + 2; }
        if (v.w >= th) { int sl = atomicAdd(&cntS[w], 1); if (sl < 64) candS[w][sl] = base + 3; }
    }
    __syncthreads();
    int cnt = min(cntS[w], 64);
    int b = row >> 8;
    int bi = candS[w][0];
    if (cnt > 1) {
        float4 t4 = ((const float4*)(txt + (long long)row * Dc))[lane];
        float it = invt[row];
        float bestv = -3.0e38f; bi = 1 << 30;
        for (int c = 0; c < cnt; c++) {
            int n = candS[w][c];
            float4 v4 = ((const float4*)(vis + ((long long)b * Nc + n) * Dc))[lane];
            float d = t4.x * v4.x + t4.y * v4.y + t4.z * v4.z + t4.w * v4.w;
            #pragma unroll
            for (int off = 32; off; off >>= 1) d += __shfl_xor(d, off);
            float val = d * it * invv[b * Nc + n];
            if (val > bestv || (val == bestv && n < bi)) { bestv = val; bi = n; }
        }
    }
    int mk = mask[row];
    if (lane == 0) {
        float tms = mk ? best : 0.0f;
        tms_out[row] = tms;
        idx_out[row] = (float)bi;
        idx_ws[row] = bi;
        float pf = fminf(fmaxf(tms, 0.0f), 1.0f);
        logits_out[row * 2 + 0] = 1.0f - pf;
        logits_out[row * 2 + 1] = pf;
    }
    if (mk == 0) {
        float4 mv = make_float4(-1.0f, -1.0f, -1.0f, -1.0f);
        #pragma unroll
        for (int s = 0; s < 4; s++) *(float4*)(srow + s * 256 + lane * 4) = mv;
    }
}

// ---------------------------------------------------------------------------
// 6) column softmax stats over m (masked sim): online single pass, float4.
//    grid (2, Bc), 128 threads; thread owns 4 consecutive n.
__global__ __launch_bounds__(128) void colstats_kernel(const float* __restrict__ sim,
                                                       float* __restrict__ cmax,
                                                       float* __restrict__ crecip) {
    int b = blockIdx.y;
    int n4 = (blockIdx.x * 128 + threadIdx.x) * 4;
    const float* base = sim + (long long)b * Mc * Nc + n4;
    float4 mx = make_float4(-3.0e38f, -3.0e38f, -3.0e38f, -3.0e38f);
    float4 s = make_float4(0.f, 0.f, 0.f, 0.f);
    for (int m = 0; m < Mc; m++) {
        float4 v = *(const float4*)(base + (long long)m * Nc);
        float nm;
        nm = fmaxf(mx.x, v.x); s.x = s.x * expf(mx.x - nm) + expf(v.x - nm); mx.x = nm;
        nm = fmaxf(mx.y, v.y); s.y = s.y * expf(mx.y - nm) + expf(v.y - nm); mx.y = nm;
        nm = fmaxf(mx.z, v.z); s.z = s.z * expf(mx.z - nm) + expf(v.z - nm); mx.z = nm;
        nm = fmaxf(mx.w, v.w); s.w = s.w * expf(mx.w - nm) + expf(v.w - nm); mx.w = nm;
    }
    *(float4*)(cmax + b * Nc + n4) = mx;
    *(float4*)(crecip + b * Nc + n4) = make_float4(1.f / s.x, 1.f / s.y, 1.f / s.z, 1.f / s.w);
}

// ---------------------------------------------------------------------------
// 7) weighted_patch MFMA GEMM: C[n][d] = sum_m P[n][m]*txt[m][d]
//    One block = 128 n x 256 d, 8 waves (2 n-halves x 4 d-quarters).
//    A (P) staged from sim (exp+cvt, reg->LDS); B (Tt) via global_load_lds.
__global__ __launch_bounds__(512) void wp_gemm(const float* __restrict__ sim,
                                               const unsigned short* __restrict__ Tt,
                                               const float* __restrict__ cmax,
                                               const float* __restrict__ crecip,
                                               float* __restrict__ wpout) {
    __shared__ unsigned short As[128 * 64];   // P tile: n x m-block
    __shared__ unsigned short Bs[256 * 64];   // Tt tile: d x m-block
    int z = blockIdx.y;
    int n0 = blockIdx.x * 128;
    const float* S = sim + (long long)z * Mc * Nc;
    const unsigned short* Bb = Tt + (long long)z * 256 * 256;
    int t = threadIdx.x;
    int lane = t & 63, wid = t >> 6;
    int wr = wid >> 2, wc = wid & 3;
    int lr = lane & 15, lk = lane >> 4;
    int nl = t & 127, mh = t >> 7;          // 4 threads per n-row, mh = m-subgroup
    float cm = cmax[(long long)z * Nc + n0 + nl];
    float cr = crecip[(long long)z * Nc + n0 + nl];
    f32x4 acc[4][4];
    #pragma unroll
    for (int i = 0; i < 4; i++)
        #pragma unroll
        for (int j = 0; j < 4; j++) acc[i][j] = (f32x4){0.f, 0.f, 0.f, 0.f};

    for (int g = 0; g < 4; g++) {   // 4 m-blocks of 64
        unsigned short pv[16];
        #pragma unroll
        for (int j = 0; j < 16; j++) {
            int m = g * 64 + mh * 16 + j;
            float v = S[(long long)m * Nc + n0 + nl];
            pv[j] = f2bf_rne(expf(v - cm) * cr);
        }
        __syncthreads();   // previous iter's LDS readers done
        #pragma unroll
        for (int i = 0; i < 4; i++) {      // B tile: 2048 chunks via gld16
            int wb = i * 512 + (t & 448);
            int c  = wb + (t & 63);
            int row = c >> 3, p = c & 7;
            gld16(Bb + (long long)row * 256 + g * 64 + ((p ^ (row & 7)) << 3), Bs + wb * 8);
        }
        #pragma unroll
        for (int q = 0; q < 2; q++) {      // A tile: reg->LDS (swizzled)
            int chunk = mh * 2 + q;
            uint4 h = make_uint4(pk2(pv[q * 8 + 0], pv[q * 8 + 1]), pk2(pv[q * 8 + 2], pv[q * 8 + 3]),
                                 pk2(pv[q * 8 + 4], pv[q * 8 + 5]), pk2(pv[q * 8 + 6], pv[q * 8 + 7]));
            *(uint4*)(As + nl * 64 + ((chunk ^ (nl & 7)) << 3)) = h;
        }
        __syncthreads();   // drains vmcnt + lgkm
        #pragma unroll
        for (int ks = 0; ks < 2; ks++) {
            bfrag av[4], bv2[4];
            #pragma unroll
            for (int f = 0; f < 4; f++) {
                int ra = wr * 64 + f * 16 + lr;
                av[f] = *(const bfrag*)(As + ra * 64 + ((((ks << 2) | lk) ^ (ra & 7)) << 3));
                int rb = wc * 64 + f * 16 + lr;
                bv2[f] = *(const bfrag*)(Bs + rb * 64 + ((((ks << 2) | lk) ^ (rb & 7)) << 3));
            }
            #pragma unroll
            for (int fm = 0; fm < 4; fm++)
                #pragma unroll
                for (int fn = 0; fn < 4; fn++)
                    acc[fm][fn] = __builtin_amdgcn_mfma_f32_16x16x32_bf16(av[fm], bv2[fn], acc[fm][fn], 0, 0, 0);
        }
    }

    float* C = wpout + (long long)z * Nc * Dc;
    int rbase = n0 + wr * 64;
    int cbase = wc * 64;
    #pragma unroll
    for (int fn = 0; fn < 4; fn++) {
        int col = cbase + fn * 16 + lr;
        #pragma unroll
        for (int fm = 0; fm < 4; fm++) {
            #pragma unroll
            for (int r = 0; r < 4; r++) {
                int row = rbase + fm * 16 + lk * 4 + r;
                C[(long long)row * Dc + col] = acc[fm][fn][r];
            }
        }
    }
}

// ---------------------------------------------------------------------------
// 8) pair_b[m] = [txt_b row | vis_b gathered row]  (wave per row)
__global__ void gatherpair_k(const unsigned short* __restrict__ txt_b,
                             const unsigned short* __restrict__ vis_b,
                             const int* __restrict__ idx_ws,
                             unsigned short* __restrict__ pair_b) {
    int wave = (blockIdx.x * blockDim.x + threadIdx.x) >> 6;
    int lane = threadIdx.x & 63;
    int b = wave >> 8;      // / Mc
    int bi = idx_ws[wave];
    int half = lane >> 5, c = lane & 31;
    const unsigned short* srcrow = half ? (vis_b + ((long long)b * Nc + bi) * 256)
                                        : (txt_b + (long long)wave * 256);
    uint4 v = *(const uint4*)(srcrow + c * 8);
    *(uint4*)(pair_b + (long long)wave * 512 + half * 256 + c * 8) = v;
}

// ---------------------------------------------------------------------------
// 9) LayerNorm + GELU: read H fp32, write bf16 H_b
__global__ void lngelu_k(const float* __restrict__ H,
                         unsigned short* __restrict__ Hb,
                         const float* __restrict__ g,
                         const float* __restrict__ bta) {
    int wave = (blockIdx.x * blockDim.x + threadIdx.x) >> 6;
    int lane = threadIdx.x & 63;
    float4 v = ((const float4*)(H + (long long)wave * Dc))[lane];
    float s = v.x + v.y + v.z + v.w;
    #pragma unroll
    for (int off = 32; off; off >>= 1) s += __shfl_xor(s, off);
    float mu = s * (1.0f / 256.0f);
    float dx = v.x - mu, dy = v.y - mu, dz = v.z - mu, dw = v.w - mu;
    float ss = dx * dx + dy * dy + dz * dz + dw * dw;
    #pragma unroll
    for (int off = 32; off; off >>= 1) ss += __shfl_xor(ss, off);
    float rstd = 1.0f / sqrtf(ss * (1.0f / 256.0f) + 1e-5f);
    float4 G4 = ((const float4*)g)[lane];
    float4 B4 = ((const float4*)bta)[lane];
    unsigned short h0 = f2bf_rne(gelu_exact(dx * rstd * G4.x + B4.x));
    unsigned short h1 = f2bf_rne(gelu_exact(dy * rstd * G4.y + B4.y));
    unsigned short h2 = f2bf_rne(gelu_exact(dz * rstd * G4.z + B4.z));
    unsigned short h3 = f2bf_rne(gelu_exact(dw * rstd * G4.w + B4.w));
    *(uint2*)(Hb + (long long)wave * 256 + lane * 4) = make_uint2(pk2(h0, h1), pk2(h2, h3));
}

// ---------------------------------------------------------------------------
// 10) per-b: gate softmax, grounding, contradiction, score MLP (512 thr/block)
__global__ __launch_bounds__(512) void final_kernel(const float* __restrict__ gate,
                                                    const int* __restrict__ mask,
                                                    const float* __restrict__ tms,
                                                    const float* __restrict__ pairO,
                                                    const float* __restrict__ Ws1,
                                                    const float* __restrict__ bs1,
                                                    const float* __restrict__ Ws2,
                                                    const float* __restrict__ bs2,
                                                    float* __restrict__ grounding_out,
                                                    float* __restrict__ score_out) {
    __shared__ float wS[256];
    __shared__ float featS[256];
    __shared__ float hS[128];
    __shared__ float red4[4];
    __shared__ float gpart[512];
    __shared__ float hpart[512];
    __shared__ float contraS;
    int b = blockIdx.x, t = threadIdx.x;
    int mk = 0; float g = -10000.0f, tmsv = 0.f;
    if (t < 256) {
        mk = mask[b * Mc + t];
        g = mk ? gate[b * Mc + t] : -10000.0f;
        tmsv = tms[b * Mc + t];
    }
    if (t < 256) {
        float mx = g;
        #pragma unroll
        for (int off = 32; off; off >>= 1) mx = fmaxf(mx, __shfl_xor(mx, off));
        if ((t & 63) == 0) red4[t >> 6] = mx;
    }
    __syncthreads();
    float mx = fmaxf(fmaxf(red4[0], red4[1]), fmaxf(red4[2], red4[3]));
    __syncthreads();
    float e = 0.f;
    if (t < 256) {
        e = expf(g - mx);
        float ssum = e;
        #pragma unroll
        for (int off = 32; off; off >>= 1) ssum += __shfl_xor(ssum, off);
        if ((t & 63) == 0) red4[t >> 6] = ssum;
    }
    __syncthreads();
    float ssum = red4[0] + red4[1] + red4[2] + red4[3];
    __syncthreads();
    float w = 0.f;
    if (t < 256) {
        w = (e / ssum) * (float)mk;
        float s2 = w;
        #pragma unroll
        for (int off = 32; off; off >>= 1) s2 += __shfl_xor(s2, off);
        if ((t & 63) == 0) red4[t >> 6] = s2;
    }
    __syncthreads();
    float s2 = red4[0] + red4[1] + red4[2] + red4[3];
    __syncthreads();
    if (t < 256) {
        w = w / fmaxf(s2, 1e-8f);
        wS[t] = w;
        float cp = tmsv * w;
        #pragma unroll
        for (int off = 32; off; off >>= 1) cp += __shfl_xor(cp, off);
        if ((t & 63) == 0) red4[t >> 6] = cp;
    }
    __syncthreads();
    if (t == 0) contraS = 1.0f - (red4[0] + red4[1] + red4[2] + red4[3]);
    __syncthreads();

    // grounding: split m over 2 halves
    int d = t & 255, half = t >> 8;
    const float* P = pairO + (long long)b * Mc * Dc;
    float acc = 0.0f;
    for (int i = 0; i < 128; i++) {
        int m = half * 128 + i;
        acc += wS[m] * P[(long long)m * Dc + d];
    }
    gpart[t] = acc;
    __syncthreads();
    if (t < 256) {
        float s = gpart[t] + gpart[t + 256];
        grounding_out[b * Dc + t] = s;
        featS[t] = s * (1.0f + contraS);
    }
    __syncthreads();

    // score MLP: 128 outputs, k split over 4 parts
    int j = t & 127, part = t >> 7;
    float a = 0.0f;
    for (int i = 0; i < 64; i++) {
        int k = part * 64 + i;
        a += featS[k] * Ws1[k * 128 + j];
    }
    hpart[t] = a;
    __syncthreads();
    if (t < 128) {
        float aa = hpart[t] + hpart[t + 128] + hpart[t + 256] + hpart[t + 384] + bs1[t];
        hS[t] = gelu_exact(aa) * Ws2[t];
    }
    __syncthreads();
    if (t < 64) {
        float s = hS[t] + hS[t + 64];
        #pragma unroll
        for (int off = 32; off; off >>= 1) s += __shfl_xor(s, off);
        if (t == 0) score_out[b] = 1.0f / (1.0f + expf(-(s + bs2[0])));
    }
}

// ---------------------------------------------------------------------------
extern "C" void kernel_launch(void* const* d_in, const int* in_sizes, int n_in,
                              void* d_out, int out_size, void* d_ws, size_t ws_size,
                              hipStream_t stream) {
    const float* vis  = (const float*)d_in[0];
    const float* txt  = (const float*)d_in[1];
    const int*   mask = (const int*)d_in[2];
    const float* Wg1  = (const float*)d_in[3];
    const float* bg1  = (const float*)d_in[4];
    const float* Wg2  = (const float*)d_in[5];
    const float* bg2  = (const float*)d_in[6];
    const float* Wo1  = (const float*)d_in[7];
    const float* bo1  = (const float*)d_in[8];
    const float* ln_g = (const float*)d_in[9];
    const float* ln_b = (const float*)d_in[10];
    const float* Wo2  = (const float*)d_in[11];
    const float* bo2  = (const float*)d_in[12];
    const float* Ws1  = (const float*)d_in[13];
    const float* bs1  = (const float*)d_in[14];
    const float* Ws2  = (const float*)d_in[15];
    const float* bs2  = (const float*)d_in[16];

    float* out = (float*)d_out;
    float* o_sim    = out;                                  // B*M*N
    float* o_tms    = o_sim + (size_t)Bc * Mc * Nc;
    float* o_idx    = o_tms + (size_t)Bc * Mc;
    float* o_logits = o_idx + (size_t)Bc * Mc;
    float* o_ground = o_logits + (size_t)Bc * Mc * 2;
    float* o_score  = o_ground + (size_t)Bc * Dc;
    float* o_wp     = o_score + (size_t)Bc;                 // B*N*D

    // Workspace layout — fully disjoint:
    char* wsb = (char*)d_ws;
    unsigned short* vis_b  = (unsigned short*)(wsb + 0);           // 67,108,864
    unsigned short* txt_b  = (unsigned short*)(wsb + 67108864);    // 16,777,216
    unsigned short* Tt     = (unsigned short*)(wsb + 83886080);    // 16,777,216
    unsigned short* pair_b = (unsigned short*)(wsb + 100663296);   // 33,554,432
    float*          H1     = (float*)(wsb + 134217728);            // 33,554,432
    unsigned short* H1_b   = (unsigned short*)(wsb + 167772160);   // 16,777,216
    float*          pairO  = (float*)(wsb + 184549376);            // 33,554,432
    unsigned short* pairO_b= (unsigned short*)(wsb + 218103808);   // 16,777,216
    char* sm = wsb + 234881024;
    float* invv    = (float*)(sm + 0);              // 524288
    float* invt    = (float*)(sm + 524288);         // 131072
    float* cmaxb   = (float*)(sm + 655360);         // 524288
    float* crecipb = (float*)(sm + 1179648);        // 524288
    int*   idx_ws  = (int*)(sm + 1703936);          // 131072
    float* gateb   = (float*)(sm + 1835008);        // 131072
    unsigned short* Wo1_t = (unsigned short*)(sm + 1966080);  // 262144
    unsigned short* Wo2_t = (unsigned short*)(sm + 2228224);  // 131072
    unsigned short* Wg1_t = (unsigned short*)(sm + 2359296);  // 131072

    // 1) normalize + bf16 convert + inv norms
    normalize_k<<<(Bc * Nc + Bc * Mc) / 4, 256, 0, stream>>>(vis, txt, vis_b, txt_b, invv, invt);
    // 2) prep: weight transposes + gate init (= bg2)
    prep_k<<<68, 256, 0, stream>>>(Wo1, Wo2, Wg1, Wo1_t, Wo2_t, Wg1_t, bg2, gateb);
    // 3) sim = txt_n @ vis_n^T  (MFMA bf16, K=256)
    gemm_nt<0><<<dim3(8, 2, 128), 256, 0, stream>>>(txt_b, vis_b, nullptr, o_sim, nullptr, nullptr, nullptr,
                                                    256, 256, 256, 1024,
                                                    256LL * 256, 1024LL * 256, 256LL * 1024);
    // 4) row stats + fp32 argmax refinement + mask sim
    rowstats_kernel<<<(Bc * Mc) / 4, 256, 0, stream>>>(o_sim, mask, txt, vis, invt, invv,
                                                       o_tms, o_idx, o_logits, idx_ws);
    // 5) column softmax stats (online, single pass)
    colstats_kernel<<<dim3(2, Bc), 128, 0, stream>>>(o_sim, cmaxb, crecipb);
    // 6) txt transpose for wp B-operand
    t_txt<<<dim3(4, 4, 128), 256, 0, stream>>>(txt_b, Tt);
    // 7) weighted_patch (MFMA, 8 waves, sim read once)
    wp_gemm<<<dim3(8, 128), 512, 0, stream>>>(o_sim, Tt, cmaxb, crecipb, o_wp);
    // 8) gather pair
    gatherpair_k<<<(Bc * Mc) / 4, 256, 0, stream>>>(txt_b, vis_b, idx_ws, pair_b);
    // 9) H1 = pair @ Wo1 + bo1  (K=512)
    gemm_nt<1><<<dim3(2, 256, 1), 256, 0, stream>>>(pair_b, Wo1_t, bo1, H1, nullptr, nullptr, nullptr,
                                                    512, 512, 512, 256, 0, 0, 0);
    // 10) LN + GELU -> H1_b
    lngelu_k<<<(Bc * Mc) / 4, 256, 0, stream>>>(H1, H1_b, ln_g, ln_b);
    // 11) pairO = H1 @ Wo2 + bo2 (f32 + bf16 out)
    gemm_nt<2><<<dim3(2, 256, 1), 256, 0, stream>>>(H1_b, Wo2_t, bo2, pairO, pairO_b, nullptr, nullptr,
                                                    256, 256, 256, 256, 0, 0, 0);
    // 12) gate += dot(gelu(pairO @ Wg1 + bg1), Wg2)  — fused epilogue, no C write
    gemm_nt<4><<<dim3(2, 256, 1), 256, 0, stream>>>(pairO_b, Wg1_t, bg1, nullptr, nullptr, Wg2, gateb,
                                                    256, 256, 256, 256, 0, 0, 0);
    // 13) finale
    final_kernel<<<Bc, 512, 0, stream>>>(gateb, mask, o_tms, pairO, Ws1, bs1, Ws2, bs2, o_ground, o_score);
}